// Round 16
// baseline (287.177 us; speedup 1.0000x reference)
//
#include <hip/hip_runtime.h>
#include <hip/hip_bf16.h>

#define CDIM   1024
#define NSEQ   2048
#define NHEAD  16
#define HDIM   64
#define MLPDIM 4096
#define TROWS  4096   // B*N = 2*2048

typedef __attribute__((ext_vector_type(8)))  __bf16 bf16x8;
typedef __attribute__((ext_vector_type(4)))  float  f32x4;
typedef __attribute__((ext_vector_type(16))) float  f32x16;
typedef __attribute__((ext_vector_type(4)))  unsigned short us4;

static __device__ __forceinline__ unsigned short f2bf(float f) {
  unsigned int u = __float_as_uint(f);
  u += 0x7fffu + ((u >> 16) & 1u);      // round-to-nearest-even
  return (unsigned short)(u >> 16);
}

#define MFMA16(a, b, c) __builtin_amdgcn_mfma_f32_16x16x32_bf16(a, b, c, 0, 0, 0)
#define MFMA32(a, b, c) __builtin_amdgcn_mfma_f32_32x32x16_bf16(a, b, c, 0, 0, 0)

// async global->LDS, 16B per lane; LDS dest must be wave-uniform (linear layout)
static __device__ __forceinline__ void gll16(const unsigned short* g, unsigned short* l) {
  __builtin_amdgcn_global_load_lds(
      (const __attribute__((address_space(1))) unsigned int*)g,
      (__attribute__((address_space(3))) unsigned int*)l, 16, 0, 0);
}

// ---------------- LayerNorm: fp32 in -> bf16 out ----------------
__global__ __launch_bounds__(256)
void ln_bf16_kernel(const float* __restrict__ x,
                    const float* __restrict__ gam,
                    const float* __restrict__ bet,
                    unsigned short* __restrict__ out)
{
  int row = blockIdx.x;
  int t = threadIdx.x;
  const float4* xr = (const float4*)(x + (size_t)row * CDIM);
  float4 v = xr[t];
  float s  = v.x + v.y + v.z + v.w;
  float s2 = v.x*v.x + v.y*v.y + v.z*v.z + v.w*v.w;
  #pragma unroll
  for (int off = 32; off > 0; off >>= 1) {
    s  += __shfl_down(s, off);
    s2 += __shfl_down(s2, off);
  }
  __shared__ float rs[4], rs2[4];
  int wave = t >> 6, lane = t & 63;
  if (lane == 0) { rs[wave] = s; rs2[wave] = s2; }
  __syncthreads();
  float fs  = rs[0] + rs[1] + rs[2] + rs[3];
  float fs2 = rs2[0] + rs2[1] + rs2[2] + rs2[3];
  float mu   = fs * (1.0f / CDIM);
  float var  = fs2 * (1.0f / CDIM) - mu * mu;
  float rstd = rsqrtf(var + 1e-5f);
  float4 gg = ((const float4*)gam)[t];
  float4 bb = ((const float4*)bet)[t];
  us4 o;
  o.x = f2bf((v.x - mu) * rstd * gg.x + bb.x);
  o.y = f2bf((v.y - mu) * rstd * gg.y + bb.y);
  o.z = f2bf((v.z - mu) * rstd * gg.z + bb.z);
  o.w = f2bf((v.w - mu) * rstd * gg.w + bb.w);
  ((us4*)(out + (size_t)row * CDIM))[t] = o;
}

// ------------- LayerNorm fused with split-K merge: v = x+pp; x=v; out=LN(v) -------------
__global__ __launch_bounds__(256)
void ln_add_bf16_kernel(float* __restrict__ x, const float* __restrict__ pp,
                        const float* __restrict__ gam, const float* __restrict__ bet,
                        unsigned short* __restrict__ out)
{
  int row = blockIdx.x;
  int t = threadIdx.x;
  float4* xr = (float4*)(x + (size_t)row * CDIM);
  const float4* pr = (const float4*)(pp + (size_t)row * CDIM);
  float4 v = xr[t];
  float4 q = pr[t];
  v.x += q.x; v.y += q.y; v.z += q.z; v.w += q.w;
  xr[t] = v;                               // merged residual written back for FC2
  float s  = v.x + v.y + v.z + v.w;
  float s2 = v.x*v.x + v.y*v.y + v.z*v.z + v.w*v.w;
  #pragma unroll
  for (int off = 32; off > 0; off >>= 1) {
    s  += __shfl_down(s, off);
    s2 += __shfl_down(s2, off);
  }
  __shared__ float rs[4], rs2[4];
  int wave = t >> 6, lane = t & 63;
  if (lane == 0) { rs[wave] = s; rs2[wave] = s2; }
  __syncthreads();
  float fs  = rs[0] + rs[1] + rs[2] + rs[3];
  float fs2 = rs2[0] + rs2[1] + rs2[2] + rs2[3];
  float mu   = fs * (1.0f / CDIM);
  float var  = fs2 * (1.0f / CDIM) - mu * mu;
  float rstd = rsqrtf(var + 1e-5f);
  float4 gg = ((const float4*)gam)[t];
  float4 bb = ((const float4*)bet)[t];
  us4 o;
  o.x = f2bf((v.x - mu) * rstd * gg.x + bb.x);
  o.y = f2bf((v.y - mu) * rstd * gg.y + bb.y);
  o.z = f2bf((v.z - mu) * rstd * gg.z + bb.z);
  o.w = f2bf((v.w - mu) * rstd * gg.w + bb.w);
  ((us4*)(out + (size_t)row * CDIM))[t] = o;
}

// ------------- weight transpose + fp32->bf16:  W[K][N] -> Wt[N][K] -------------
__global__ __launch_bounds__(256)
void wt_bf16_kernel(const float* __restrict__ W, unsigned short* __restrict__ Wt,
                    int K, int N)
{
  __shared__ float tile[32][33];
  int n0 = blockIdx.x * 32, k0 = blockIdx.y * 32;
  int t = threadIdx.x;
  int r = t >> 3, c4 = (t & 7) << 2;
  float4 v = *(const float4*)(W + (size_t)(k0 + r) * N + n0 + c4);
  tile[r][c4 + 0] = v.x; tile[r][c4 + 1] = v.y;
  tile[r][c4 + 2] = v.z; tile[r][c4 + 3] = v.w;
  __syncthreads();
  us4 o;
  o.x = f2bf(tile[c4 + 0][r]);
  o.y = f2bf(tile[c4 + 1][r]);
  o.z = f2bf(tile[c4 + 2][r]);
  o.w = f2bf(tile[c4 + 3][r]);
  *(us4*)(Wt + (size_t)(n0 + r) * K + k0 + c4) = o;
}

// ---------------- GEMM 128x128 (QKV only): 2-buffer dbuf, XCD-swizzled ----------------
// EPI 1: qkv split, sel = bx>>3 is BLOCK-UNIFORM (nbx=24): q*log2e / k scalar writes;
//        V blocks transpose via swizzled LDS (reusing As/Bs) then write vt coalesced.
__global__ __launch_bounds__(256, 4)
void gemm_bt(const unsigned short* __restrict__ A, const unsigned short* __restrict__ Bt,
             const float* __restrict__ bias, int Kstride, int Kc, int nbx, int nby,
             unsigned short* __restrict__ qo, unsigned short* __restrict__ ko,
             unsigned short* __restrict__ vo)
{
  __shared__ unsigned short As[2][128 * 32];   // linear [128][32] (global_load_lds order)
  __shared__ unsigned short Bs[2][128 * 32];
  const int tid  = threadIdx.x;
  const int lane = tid & 63;
  const int wave = tid >> 6;
  const int wr = wave >> 1, wc = wave & 1;      // 2x2 waves, 64x64 each
  const int g = lane >> 4, r16 = lane & 15;

  const int nwg = gridDim.x;
  const int orig = ((int)blockIdx.x & 7) * (nwg >> 3) + ((int)blockIdx.x >> 3);
  const int bx = orig % nbx;
  const int by = orig / nbx;
  const int bm = by * 128, bn = bx * 128;

  // stage K-tile k0 into buffer d
  auto stage = [&](int d, int k0) {
    #pragma unroll
    for (int c = 0; c < 2; c++) {
      int o   = (c * 256 + tid) << 3;          // this lane's element offset in 128x32 tile
      int row = o >> 5;
      int col = o & 31;
      int ub  = (c * 256 + (tid & ~63)) << 3;  // wave-uniform LDS element base
      gll16(A  + (size_t)(bm + row) * Kstride + k0 + col, &As[d][ub]);
      gll16(Bt + (size_t)(bn + row) * Kstride + k0 + col, &Bs[d][ub]);
    }
  };

  f32x4 acc[4][4];
  #pragma unroll
  for (int i = 0; i < 4; i++)
    #pragma unroll
    for (int j = 0; j < 4; j++) acc[i][j] = (f32x4){0.f, 0.f, 0.f, 0.f};

  stage(0, 0);
  const int nkt = Kc / 32;
  for (int kt = 0; kt < nkt; kt++) {
    const int cur = kt & 1;
    __syncthreads();                       // buf[cur] staged (vmcnt drained); prev reads done
    if (kt + 1 < nkt) stage(cur ^ 1, (kt + 1) * 32);   // overlaps with compute below
    bf16x8 af[4], bfr[4];
    #pragma unroll
    for (int i = 0; i < 4; i++) {
      int row = wr * 64 + i * 16 + r16;
      af[i] = *(const bf16x8*)(&As[cur][row * 32 + 8 * g]);
    }
    #pragma unroll
    for (int j = 0; j < 4; j++) {
      int row = wc * 64 + j * 16 + r16;
      bfr[j] = *(const bf16x8*)(&Bs[cur][row * 32 + 8 * g]);
    }
    __builtin_amdgcn_s_setprio(1);
    #pragma unroll
    for (int i = 0; i < 4; i++)
      #pragma unroll
      for (int j = 0; j < 4; j++)
        acc[i][j] = MFMA16(af[i], bfr[j], acc[i][j]);
    __builtin_amdgcn_s_setprio(0);
  }

  if (bn >= 2048) {
    // ---- pure-V block: bias add -> swizzled LDS transpose -> coalesced vt write ----
    unsigned short* T = (unsigned short*)&As[0][0];   // 128x128 bf16 = 32 KB (As+Bs)
    __syncthreads();                                  // all waves done reading As/Bs
    #pragma unroll
    for (int i = 0; i < 4; i++) {
      #pragma unroll
      for (int j = 0; j < 4; j++) {
        int col_l = wc * 64 + j * 16 + r16;
        float bv = bias[bn + col_l];
        #pragma unroll
        for (int jj = 0; jj < 4; jj++) {
          int row = wr * 64 + i * 16 + 4 * g + jj;
          // element (col,row) at byte col*256 + (row*2 ^ ((col&7)<<4))
          *(unsigned short*)((char*)T + col_l * 256 + ((row * 2) ^ ((col_l & 7) << 4))) =
              f2bf(acc[i][j][jj] + bv);
        }
      }
    }
    __syncthreads();
    int bb = bm >> 11, tk0 = bm & 2047;               // block never straddles batch
    #pragma unroll
    for (int c = 0; c < 32; c++) {
      int col_l = wave * 32 + c;
      int cv = (bn - 2048) + col_l;
      int hh = cv >> 6, d = cv & 63;
      // token-pair a=lane lives at byte (4*lane)^swz (swz flips bits>=4 only)
      unsigned v2 = *(unsigned*)((char*)T + col_l * 256 + ((lane * 4) ^ ((col_l & 7) << 4)));
      *(unsigned*)(vo + ((size_t)(bb * NHEAD + hh) * HDIM + d) * NSEQ + tk0 + lane * 2) = v2;
    }
    return;
  }

  #pragma unroll
  for (int i = 0; i < 4; i++) {
    #pragma unroll
    for (int j = 0; j < 4; j++) {
      int col = bn + wc * 64 + j * 16 + r16;
      float bv = bias[col];
      #pragma unroll
      for (int jj = 0; jj < 4; jj++) {
        int row = bm + wr * 64 + i * 16 + 4 * g + jj;
        float val = acc[i][j][jj] + bv;
        int cc = col & 1023;
        int hh = cc >> 6, d = cc & 63;
        int b = row >> 11, tk = row & 2047;
        size_t hb = (size_t)(b * NHEAD + hh);
        if (col < 1024) qo[(hb * NSEQ + tk) * HDIM + d] = f2bf(val * 1.4426950408889634f);
        else            ko[(hb * NSEQ + tk) * HDIM + d] = f2bf(val);
      }
    }
  }
}

// ---------------- GEMM 128x64 (proj, FC1, FC2): 2-phase, 24 KB LDS, 6 blocks/CU ----------
// Same sync skeleton as gemm_bt; BN=64 doubles grid -> occupancy ~6/CU where grid allows.
// Waves 2x2 of (64 rows x 32 cols): acc[4][2], 8 MFMA/K-step.
// EPI 2: kz==0 -> outf = val+bias+resid; kz!=0 -> pp = val.  EPI 3: tanh-GELU -> outb.
template<int EPI>
__global__ __launch_bounds__(256, 6)
void gemm_bt64(const unsigned short* __restrict__ A, const unsigned short* __restrict__ Bt,
               const float* __restrict__ bias, int Kstride, int Kc, int nbx, int nby,
               float* __restrict__ outf, unsigned short* __restrict__ outb,
               const float* __restrict__ resid, float* __restrict__ pp)
{
  __shared__ unsigned short As[2][128 * 32];   // 16 KB
  __shared__ unsigned short Bs[2][64 * 32];    //  8 KB
  const int tid  = threadIdx.x;
  const int lane = tid & 63;
  const int wave = tid >> 6;
  const int wr = wave >> 1, wc = wave & 1;      // 2x2 waves, 64 rows x 32 cols each
  const int g = lane >> 4, r16 = lane & 15;

  const int nwg = gridDim.x;
  const int orig = ((int)blockIdx.x & 7) * (nwg >> 3) + ((int)blockIdx.x >> 3);
  const int bx = orig % nbx;
  const int t2 = orig / nbx;
  const int by = t2 % nby;
  const int kz = t2 / nby;
  const int bm = by * 128, bn = bx * 64;
  const int kbase = kz * Kc;
  const int N = nbx * 64;

  // stage K-tile (kbase + k0) into buffer d: 2 A-chunks + 1 B-chunk per lane
  auto stage = [&](int d, int k0) {
    #pragma unroll
    for (int c = 0; c < 2; c++) {
      int o   = (c * 256 + tid) << 3;          // element offset in 128x32 A-tile
      int row = o >> 5;
      int col = o & 31;
      int ub  = (c * 256 + (tid & ~63)) << 3;
      gll16(A + (size_t)(bm + row) * Kstride + kbase + k0 + col, &As[d][ub]);
    }
    {
      int o   = tid << 3;                      // element offset in 64x32 B-tile
      int row = o >> 5;
      int col = o & 31;
      int ub  = (tid & ~63) << 3;
      gll16(Bt + (size_t)(bn + row) * Kstride + kbase + k0 + col, &Bs[d][ub]);
    }
  };

  f32x4 acc[4][2];
  #pragma unroll
  for (int i = 0; i < 4; i++)
    #pragma unroll
    for (int j = 0; j < 2; j++) acc[i][j] = (f32x4){0.f, 0.f, 0.f, 0.f};

  stage(0, 0);
  const int nkt = Kc / 32;
  for (int kt = 0; kt < nkt; kt++) {
    const int cur = kt & 1;
    __syncthreads();                       // buf[cur] staged (vmcnt drained); prev reads done
    if (kt + 1 < nkt) stage(cur ^ 1, (kt + 1) * 32);   // overlaps with compute below
    bf16x8 af[4], bfr[2];
    #pragma unroll
    for (int i = 0; i < 4; i++) {
      int row = wr * 64 + i * 16 + r16;
      af[i] = *(const bf16x8*)(&As[cur][row * 32 + 8 * g]);
    }
    #pragma unroll
    for (int j = 0; j < 2; j++) {
      int row = wc * 32 + j * 16 + r16;
      bfr[j] = *(const bf16x8*)(&Bs[cur][row * 32 + 8 * g]);
    }
    __builtin_amdgcn_s_setprio(1);
    #pragma unroll
    for (int i = 0; i < 4; i++)
      #pragma unroll
      for (int j = 0; j < 2; j++)
        acc[i][j] = MFMA16(af[i], bfr[j], acc[i][j]);
    __builtin_amdgcn_s_setprio(0);
  }

  #pragma unroll
  for (int i = 0; i < 4; i++) {
    #pragma unroll
    for (int j = 0; j < 2; j++) {
      int col = bn + wc * 32 + j * 16 + r16;
      float bv = (EPI == 2 && kz != 0) ? 0.f : bias[col];
      #pragma unroll
      for (int jj = 0; jj < 4; jj++) {
        int row = bm + wr * 64 + i * 16 + 4 * g + jj;
        float val = acc[i][j][jj] + bv;
        if (EPI == 2) {
          size_t idx = (size_t)row * N + col;
          if (kz == 0) outf[idx] = val + resid[idx];
          else         pp[idx]   = val;
        } else {
          // tanh-approx GELU via exp2: ge = v - v/(1+exp2(2.3022*v + 0.10294*v^3))
          float vv = val * val;
          float u2 = val * (2.3022361f + 0.1029445f * vv);
          float ge = val - val / (1.0f + exp2f(u2));
          outb[(size_t)row * N + col] = f2bf(ge);
        }
      }
    }
  }
}

// ---------------- split-K merge: out[i] += pp[i] ----------------
__global__ __launch_bounds__(256)
void add_kernel(float* __restrict__ out, const float* __restrict__ pp, int n4)
{
  int i = blockIdx.x * 256 + threadIdx.x;
  int stride = gridDim.x * 256;
  for (; i < n4; i += stride) {
    float4 a = ((const float4*)out)[i];
    float4 b = ((const float4*)pp)[i];
    a.x += b.x; a.y += b.y; a.z += b.z; a.w += b.w;
    ((float4*)out)[i] = a;
  }
}

// ---------------- flash attention, swapped-operand 32x32, static-bias softmax, KV-split ----
// R13/R15-verified structure (70 us): KVBLK=32, 32 KB LDS, 4 blocks/CU.
__global__ __launch_bounds__(256, 4)
void attn_kernel(const unsigned short* __restrict__ q, const unsigned short* __restrict__ k,
                 const unsigned short* __restrict__ vt, unsigned short* __restrict__ y)
{
  int bid = blockIdx.x;                 // 1024 blocks
  int xcd = bid & 7, loc = bid >> 3;    // round-robin dispatch: bid%8 = XCD
  int bh  = xcd * 4 + (loc >> 5);       // 4 (b,h) pairs per XCD -> 2MB K/V, L2-resident
  int qb64 = loc & 31;                  // 32 q-chunks of 64 rows per bh
  int b = bh >> 4, h = bh & 15;
  int wave = threadIdx.x >> 6, lane = threadIdx.x & 63;
  int qt = wave >> 1, kvh = wave & 1;   // q-tile, kv-half
  int ql = lane & 31;
  int hi = lane >> 5;
  int q0 = qb64 * 64 + qt * 32;
  const int kvbase = kvh * (NSEQ / 2);
  const unsigned short* qb = q  + (size_t)bh * NSEQ * HDIM;
  const unsigned short* kb = k  + (size_t)bh * NSEQ * HDIM;
  const unsigned short* vb = vt + (size_t)bh * HDIM * NSEQ;

  // Per-half double-buffered tiles. K: [32 kv][8 chunks], chunk col ^= (row&7).
  // V: [64 d][4 chunks], chunk col ^= ((row>>1)&3). Linear dest for gll16.
  __shared__ unsigned short KL[2][2][2048];   // [kvh][dbuf]  16 KB
  __shared__ unsigned short VL[2][2][2048];   // 16 KB

  // stage tile 'it' (within this wave's half) into buffer d; the half's 2 waves
  // (qt=0,1) each issue 2 K-chunks + 2 V-chunks covering the 256-chunk tile.
  auto stage = [&](int d, int it) {
    int kv0 = kvbase + it * 32;
    #pragma unroll
    for (int i = 0; i < 2; i++) {
      int c = i * 128 + qt * 64 + lane;           // chunk 0..255
      int row = c >> 3, col = c & 7;
      int sc  = (row << 3) | (col ^ (row & 7));   // inverse-swizzled source chunk
      gll16(kb + (size_t)kv0 * HDIM + sc * 8, &KL[kvh][d][(i * 128 + qt * 64) * 8]);
    }
    #pragma unroll
    for (int i = 0; i < 2; i++) {
      int c = i * 128 + qt * 64 + lane;
      int row = c >> 2, col = c & 3;
      int scol = col ^ ((row >> 1) & 3);
      gll16(vb + (size_t)row * NSEQ + kv0 + scol * 8, &VL[kvh][d][(i * 128 + qt * 64) * 8]);
    }
  };

  // Q B-fragments: lane holds Q[q0+ql][s*16 + hi*8 .. +8]
  bf16x8 aq[4];
  #pragma unroll
  for (int s = 0; s < 4; s++)
    aq[s] = *(const bf16x8*)(qb + (size_t)(q0 + ql) * HDIM + s * 16 + hi * 8);

  float ssum = 0.f;
  f32x16 o0, o1;
  #pragma unroll
  for (int r = 0; r < 16; r++) { o0[r] = 0.f; o1[r] = 0.f; }

  stage(0, 0);
  const int nit = NSEQ / 64;            // 32 iters over this wave's kv-half
  for (int it = 0; it < nit; it++) {
    const int cur = it & 1;
    __syncthreads();                   // buf[cur] staged (vmcnt drained); prev reads done
    if (it + 1 < nit) stage(cur ^ 1, it + 1);   // overlaps with compute below
    // ---- K fragments from LDS (swizzled read) ----
    bf16x8 kf[4];
    #pragma unroll
    for (int s = 0; s < 4; s++)
      kf[s] = *(const bf16x8*)((const char*)KL[kvh][cur] +
               ql * 128 + ((((s << 1) | hi) ^ (ql & 7)) << 4));
    // ---- S^T[32k][32q] over d=64 (4 slices); C-input pre-biased to -32 ----
    f32x16 sacc;
    #pragma unroll
    for (int r = 0; r < 16; r++) sacc[r] = -32.0f;
    __builtin_amdgcn_s_setprio(1);
    #pragma unroll
    for (int s = 0; s < 4; s++)
      sacc = MFMA32(kf[s], aq[s], sacc);
    __builtin_amdgcn_s_setprio(0);
    // ---- static-bias softmax: P = exp2(S'-32), per-lane denominator only ----
    float ps = 0.f;
    #pragma unroll
    for (int r = 0; r < 16; r++) {
      sacc[r] = exp2f(sacc[r]);
      ps += sacc[r];
    }
    ssum += ps;
    // ---- V fragments from LDS (swizzled read) ----
    bf16x8 vf[2][2];
    #pragma unroll
    for (int t = 0; t < 2; t++)
      #pragma unroll
      for (int db = 0; db < 2; db++)
        vf[t][db] = *(const bf16x8*)((const char*)VL[kvh][cur] +
                     (db * 32 + ql) * 64 + ((((t << 1) | hi) ^ ((ql >> 1) & 3)) << 4));
    // ---- P -> bf16 fragments: cvt_pk pairs + permlane32_swap; PV ----
    __builtin_amdgcn_s_setprio(1);
    #pragma unroll
    for (int t = 0; t < 2; t++) {
      unsigned pk01, pk23, pk45, pk67;
      asm("v_cvt_pk_bf16_f32 %0, %1, %2" : "=v"(pk01) : "v"(sacc[8*t+0]), "v"(sacc[8*t+1]));
      asm("v_cvt_pk_bf16_f32 %0, %1, %2" : "=v"(pk23) : "v"(sacc[8*t+2]), "v"(sacc[8*t+3]));
      asm("v_cvt_pk_bf16_f32 %0, %1, %2" : "=v"(pk45) : "v"(sacc[8*t+4]), "v"(sacc[8*t+5]));
      asm("v_cvt_pk_bf16_f32 %0, %1, %2" : "=v"(pk67) : "v"(sacc[8*t+6]), "v"(sacc[8*t+7]));
      // vdst.hi <-> vsrc.lo:  pk01 -> {pk01_lo, pk45_lo} = u0,  pk45 -> {pk01_hi, pk45_hi} = u2
      asm("v_permlane32_swap_b32 %0, %1" : "+v"(pk01), "+v"(pk45));
      asm("v_permlane32_swap_b32 %0, %1" : "+v"(pk23), "+v"(pk67));
      union { unsigned u[4]; bf16x8 v; } pf;
      pf.u[0] = pk01; pf.u[1] = pk23; pf.u[2] = pk45; pf.u[3] = pk67;
      o0 = MFMA32(vf[t][0], pf.v, o0);
      o1 = MFMA32(vf[t][1], pf.v, o1);
    }
    __builtin_amdgcn_s_setprio(0);
  }

  // ---- merge kv-half partners: plain addition (no max state) ----
  __syncthreads();                      // all waves done with KL/VL
  float* OM = (float*)&KL[0][0][0];     // 4096 floats: [r 0..31][128 lanes], conflict-free
  float* SM = (float*)&VL[0][0][0];     // 128 floats
  if (kvh == 1) {
    #pragma unroll
    for (int r = 0; r < 16; r++) {
      OM[r * 128 + qt * 64 + lane]        = o0[r];
      OM[(16 + r) * 128 + qt * 64 + lane] = o1[r];
    }
    SM[qt * 64 + lane] = ssum;
  }
  __syncthreads();
  if (kvh == 0) {
    float st = ssum + SM[qt * 64 + lane];
    st += __shfl_xor(st, 32);           // combine lane k-subset halves
    float inv = 1.0f / st;
    #pragma unroll
    for (int r = 0; r < 16; r++) {
      o0[r] += OM[r * 128 + qt * 64 + lane];
      o1[r] += OM[(16 + r) * 128 + qt * 64 + lane];
    }
    // O^T: lane col q=ql, rows d = db*32 + (r&3)+8*(r>>2)+4*hi
    unsigned short* yr = y + ((size_t)(b * NSEQ + q0 + ql)) * CDIM + h * HDIM;
    #pragma unroll
    for (int db = 0; db < 2; db++) {
      const f32x16& oo = db ? o1 : o0;
      #pragma unroll
      for (int rq = 0; rq < 4; rq++) {
        us4 w;
        w.x = f2bf(oo[4*rq+0] * inv);
        w.y = f2bf(oo[4*rq+1] * inv);
        w.z = f2bf(oo[4*rq+2] * inv);
        w.w = f2bf(oo[4*rq+3] * inv);
        *(us4*)(yr + db * 32 + rq * 8 + hi * 4) = w;
      }
    }
  }
}

extern "C" void kernel_launch(void* const* d_in, const int* in_sizes, int n_in,
                              void* d_out, int out_size, void* d_ws, size_t ws_size,
                              hipStream_t stream)
{
  const float* x      = (const float*)d_in[0];
  const float* ln1_g  = (const float*)d_in[1];
  const float* ln1_b  = (const float*)d_in[2];
  const float* qkv_w  = (const float*)d_in[3];
  const float* qkv_b  = (const float*)d_in[4];
  const float* proj_w = (const float*)d_in[5];
  const float* proj_b = (const float*)d_in[6];
  const float* ln2_g  = (const float*)d_in[7];
  const float* ln2_b  = (const float*)d_in[8];
  const float* fc1_w  = (const float*)d_in[9];
  const float* fc1_b  = (const float*)d_in[10];
  const float* fc2_w  = (const float*)d_in[11];
  const float* fc2_b  = (const float*)d_in[12];
  float* out = (float*)d_out;

  char* p = (char*)d_ws;
  size_t off = 0;
  auto alloc = [&](size_t bytes) -> void* {
    void* r = p + off; off += (bytes + 255) & ~(size_t)255; return r;
  };
  unsigned short* wt_qkv  = (unsigned short*)alloc((size_t)3072 * 1024 * 2);
  unsigned short* wt_proj = (unsigned short*)alloc((size_t)1024 * 1024 * 2);
  unsigned short* wt_fc1  = (unsigned short*)alloc((size_t)4096 * 1024 * 2);
  unsigned short* wt_fc2  = (unsigned short*)alloc((size_t)1024 * 4096 * 2);
  unsigned short* h1  = (unsigned short*)alloc((size_t)TROWS * CDIM * 2);
  unsigned short* qb  = (unsigned short*)alloc((size_t)TROWS * CDIM * 2);
  unsigned short* kb  = (unsigned short*)alloc((size_t)TROWS * CDIM * 2);
  unsigned short* vtb = (unsigned short*)alloc((size_t)TROWS * CDIM * 2);
  unsigned short* yb  = (unsigned short*)alloc((size_t)TROWS * CDIM * 2);
  float*          x1  = (float*)alloc((size_t)TROWS * CDIM * 4);
  unsigned short* h2  = (unsigned short*)alloc((size_t)TROWS * CDIM * 2);
  unsigned short* g1  = (unsigned short*)alloc((size_t)TROWS * MLPDIM * 2);
  // split-K partial (proj & FC2, sequential uses): aliases qb+kb (dead after attention)
  float* pp = (float*)qb;

  dim3 blk(256);
  // weight transpose + bf16
  wt_bf16_kernel<<<dim3(3072 / 32, 1024 / 32), blk, 0, stream>>>(qkv_w, wt_qkv, 1024, 3072);
  wt_bf16_kernel<<<dim3(1024 / 32, 1024 / 32), blk, 0, stream>>>(proj_w, wt_proj, 1024, 1024);
  wt_bf16_kernel<<<dim3(4096 / 32, 1024 / 32), blk, 0, stream>>>(fc1_w, wt_fc1, 1024, 4096);
  wt_bf16_kernel<<<dim3(1024 / 32, 4096 / 32), blk, 0, stream>>>(fc2_w, wt_fc2, 4096, 1024);
  // LN1
  ln_bf16_kernel<<<TROWS, blk, 0, stream>>>(x, ln1_g, ln1_b, h1);
  // QKV (q pre-scaled by log2e): nbx=24, nby=32, grid 768
  gemm_bt<<<dim3(768), blk, 0, stream>>>(
      h1, wt_qkv, qkv_b, 1024, 1024, 24, 32, qb, kb, vtb);
  // attention (flat 1024-block grid, XCD-clustered, KV-split, KVBLK=32)
  attn_kernel<<<dim3(1024), blk, 0, stream>>>(qb, kb, vtb, yb);
  // proj + residual -> x1 (fp32), BN=64, split-K=2: nbx=16, nby=32, grid 1024
  gemm_bt64<2><<<dim3(1024), blk, 0, stream>>>(
      yb, wt_proj, proj_b, 1024, 512, 16, 32,
      x1, nullptr, x, pp);
  // LN2 fused with proj split-K merge: x1 += pp; h2 = LN(x1)
  ln_add_bf16_kernel<<<TROWS, blk, 0, stream>>>(x1, pp, ln2_g, ln2_b, h2);
  // FC1 + tanh-GELU -> g1 (bf16), BN=64: nbx=64, nby=32, grid 2048
  gemm_bt64<3><<<dim3(2048), blk, 0, stream>>>(
      h2, wt_fc1, fc1_b, 1024, 1024, 64, 32,
      nullptr, g1, nullptr, nullptr);
  // FC2 + residual -> out (fp32), BN=64, split-K=2: nbx=16, nby=32, grid 1024
  gemm_bt64<2><<<dim3(1024), blk, 0, stream>>>(
      g1, wt_fc2, fc2_b, 4096, 2048, 16, 32,
      out, nullptr, x1, pp);
  // merge split-K partial: out += pp (4M floats = 1M float4)
  add_kernel<<<dim3(2048), blk, 0, stream>>>(out, pp, TROWS * CDIM / 4);
}

// Round 17
// 276.076 us; speedup vs baseline: 1.0402x; 1.0402x over previous
//
#include <hip/hip_runtime.h>
#include <hip/hip_bf16.h>

#define CDIM   1024
#define NSEQ   2048
#define NHEAD  16
#define HDIM   64
#define MLPDIM 4096
#define TROWS  4096   // B*N = 2*2048

typedef __attribute__((ext_vector_type(8)))  __bf16 bf16x8;
typedef __attribute__((ext_vector_type(4)))  float  f32x4;
typedef __attribute__((ext_vector_type(16))) float  f32x16;
typedef __attribute__((ext_vector_type(4)))  unsigned short us4;

static __device__ __forceinline__ unsigned short f2bf(float f) {
  unsigned int u = __float_as_uint(f);
  u += 0x7fffu + ((u >> 16) & 1u);      // round-to-nearest-even
  return (unsigned short)(u >> 16);
}

#define MFMA16(a, b, c) __builtin_amdgcn_mfma_f32_16x16x32_bf16(a, b, c, 0, 0, 0)
#define MFMA32(a, b, c) __builtin_amdgcn_mfma_f32_32x32x16_bf16(a, b, c, 0, 0, 0)

// async global->LDS, 16B per lane; LDS dest must be wave-uniform (linear layout)
static __device__ __forceinline__ void gll16(const unsigned short* g, unsigned short* l) {
  __builtin_amdgcn_global_load_lds(
      (const __attribute__((address_space(1))) unsigned int*)g,
      (__attribute__((address_space(3))) unsigned int*)l, 16, 0, 0);
}

// ---------------- LayerNorm: fp32 in -> bf16 out ----------------
__global__ __launch_bounds__(256)
void ln_bf16_kernel(const float* __restrict__ x,
                    const float* __restrict__ gam,
                    const float* __restrict__ bet,
                    unsigned short* __restrict__ out)
{
  int row = blockIdx.x;
  int t = threadIdx.x;
  const float4* xr = (const float4*)(x + (size_t)row * CDIM);
  float4 v = xr[t];
  float s  = v.x + v.y + v.z + v.w;
  float s2 = v.x*v.x + v.y*v.y + v.z*v.z + v.w*v.w;
  #pragma unroll
  for (int off = 32; off > 0; off >>= 1) {
    s  += __shfl_down(s, off);
    s2 += __shfl_down(s2, off);
  }
  __shared__ float rs[4], rs2[4];
  int wave = t >> 6, lane = t & 63;
  if (lane == 0) { rs[wave] = s; rs2[wave] = s2; }
  __syncthreads();
  float fs  = rs[0] + rs[1] + rs[2] + rs[3];
  float fs2 = rs2[0] + rs2[1] + rs2[2] + rs2[3];
  float mu   = fs * (1.0f / CDIM);
  float var  = fs2 * (1.0f / CDIM) - mu * mu;
  float rstd = rsqrtf(var + 1e-5f);
  float4 gg = ((const float4*)gam)[t];
  float4 bb = ((const float4*)bet)[t];
  us4 o;
  o.x = f2bf((v.x - mu) * rstd * gg.x + bb.x);
  o.y = f2bf((v.y - mu) * rstd * gg.y + bb.y);
  o.z = f2bf((v.z - mu) * rstd * gg.z + bb.z);
  o.w = f2bf((v.w - mu) * rstd * gg.w + bb.w);
  ((us4*)(out + (size_t)row * CDIM))[t] = o;
}

// ------------- LayerNorm fused with split-K merge: v = x+pp; x=v; out=LN(v) -------------
__global__ __launch_bounds__(256)
void ln_add_bf16_kernel(float* __restrict__ x, const float* __restrict__ pp,
                        const float* __restrict__ gam, const float* __restrict__ bet,
                        unsigned short* __restrict__ out)
{
  int row = blockIdx.x;
  int t = threadIdx.x;
  float4* xr = (float4*)(x + (size_t)row * CDIM);
  const float4* pr = (const float4*)(pp + (size_t)row * CDIM);
  float4 v = xr[t];
  float4 q = pr[t];
  v.x += q.x; v.y += q.y; v.z += q.z; v.w += q.w;
  xr[t] = v;                               // merged residual written back for FC2
  float s  = v.x + v.y + v.z + v.w;
  float s2 = v.x*v.x + v.y*v.y + v.z*v.z + v.w*v.w;
  #pragma unroll
  for (int off = 32; off > 0; off >>= 1) {
    s  += __shfl_down(s, off);
    s2 += __shfl_down(s2, off);
  }
  __shared__ float rs[4], rs2[4];
  int wave = t >> 6, lane = t & 63;
  if (lane == 0) { rs[wave] = s; rs2[wave] = s2; }
  __syncthreads();
  float fs  = rs[0] + rs[1] + rs[2] + rs[3];
  float fs2 = rs2[0] + rs2[1] + rs2[2] + rs2[3];
  float mu   = fs * (1.0f / CDIM);
  float var  = fs2 * (1.0f / CDIM) - mu * mu;
  float rstd = rsqrtf(var + 1e-5f);
  float4 gg = ((const float4*)gam)[t];
  float4 bb = ((const float4*)bet)[t];
  us4 o;
  o.x = f2bf((v.x - mu) * rstd * gg.x + bb.x);
  o.y = f2bf((v.y - mu) * rstd * gg.y + bb.y);
  o.z = f2bf((v.z - mu) * rstd * gg.z + bb.z);
  o.w = f2bf((v.w - mu) * rstd * gg.w + bb.w);
  ((us4*)(out + (size_t)row * CDIM))[t] = o;
}

// ------------- fused weight transpose + fp32->bf16 for all four weights -------------
// flat grid of 32x32 tiles: [0,3072) qkv  [3072,4096) proj  [4096,8192) fc1  [8192,12288) fc2
__global__ __launch_bounds__(256)
void wt_all_kernel(const float* __restrict__ W0, unsigned short* __restrict__ T0,
                   const float* __restrict__ W1, unsigned short* __restrict__ T1,
                   const float* __restrict__ W2, unsigned short* __restrict__ T2,
                   const float* __restrict__ W3, unsigned short* __restrict__ T3)
{
  int id = blockIdx.x;
  const float* W; unsigned short* Wt; int K, N, nx;
  if (id < 3072)      { W = W0; Wt = T0; K = 1024; N = 3072; nx = 96; }
  else if (id < 4096) { W = W1; Wt = T1; K = 1024; N = 1024; nx = 32; id -= 3072; }
  else if (id < 8192) { W = W2; Wt = T2; K = 1024; N = 4096; nx = 128; id -= 4096; }
  else                { W = W3; Wt = T3; K = 4096; N = 1024; nx = 32; id -= 8192; }
  int n0 = (id % nx) * 32, k0 = (id / nx) * 32;

  __shared__ float tile[32][33];
  int t = threadIdx.x;
  int r = t >> 3, c4 = (t & 7) << 2;
  float4 v = *(const float4*)(W + (size_t)(k0 + r) * N + n0 + c4);
  tile[r][c4 + 0] = v.x; tile[r][c4 + 1] = v.y;
  tile[r][c4 + 2] = v.z; tile[r][c4 + 3] = v.w;
  __syncthreads();
  us4 o;
  o.x = f2bf(tile[c4 + 0][r]);
  o.y = f2bf(tile[c4 + 1][r]);
  o.z = f2bf(tile[c4 + 2][r]);
  o.w = f2bf(tile[c4 + 3][r]);
  *(us4*)(Wt + (size_t)(n0 + r) * K + k0 + c4) = o;
}

// ---------------- GEMM: C = A * Bt^T (+bias), fused epilogues, XCD-swizzled, split-K ----
// 2-buffer LDS dbuf (R11-verified): barrier -> issue stage(kt+1) -> compute(kt).
// Flattened grid: orig = (bid&7)*(nwg/8) + bid>>3  (XCD-chunk swizzle; nwg % 8 == 0).
// orig -> bx (N-tile, fast), by (M-tile), kz (K-chunk).
// EPI 1: qkv split, sel = bx>>3 is BLOCK-UNIFORM (nbx=24): q*log2e / k scalar writes;
//        V blocks transpose via swizzled LDS (reusing As/Bs) then write vt coalesced.
// EPI 2: kz==0 -> outf = val+bias+resid; kz!=0 -> pp = val.  EPI 3: tanh-GELU -> outb.
template<int EPI>
__global__ __launch_bounds__(256, 4)
void gemm_bt(const unsigned short* __restrict__ A, const unsigned short* __restrict__ Bt,
             const float* __restrict__ bias, int Kstride, int Kc, int nbx, int nby,
             float* __restrict__ outf, unsigned short* __restrict__ outb,
             const float* __restrict__ resid, float* __restrict__ pp,
             unsigned short* __restrict__ qo, unsigned short* __restrict__ ko,
             unsigned short* __restrict__ vo)
{
  __shared__ unsigned short As[2][128 * 32];   // linear [128][32] (global_load_lds order)
  __shared__ unsigned short Bs[2][128 * 32];
  const int tid  = threadIdx.x;
  const int lane = tid & 63;
  const int wave = tid >> 6;
  const int wr = wave >> 1, wc = wave & 1;      // 2x2 waves, 64x64 each
  const int g = lane >> 4, r16 = lane & 15;

  const int nwg = gridDim.x;
  const int orig = ((int)blockIdx.x & 7) * (nwg >> 3) + ((int)blockIdx.x >> 3);
  const int bx = orig % nbx;
  const int t2 = orig / nbx;
  const int by = t2 % nby;
  const int kz = t2 / nby;
  const int bm = by * 128, bn = bx * 128;
  const int kbase = kz * Kc;
  const int N = nbx * 128;

  // stage K-tile (kbase + k0) into buffer d
  auto stage = [&](int d, int k0) {
    #pragma unroll
    for (int c = 0; c < 2; c++) {
      int o   = (c * 256 + tid) << 3;          // this lane's element offset in 128x32 tile
      int row = o >> 5;
      int col = o & 31;
      int ub  = (c * 256 + (tid & ~63)) << 3;  // wave-uniform LDS element base
      gll16(A  + (size_t)(bm + row) * Kstride + kbase + k0 + col, &As[d][ub]);
      gll16(Bt + (size_t)(bn + row) * Kstride + kbase + k0 + col, &Bs[d][ub]);
    }
  };

  f32x4 acc[4][4];
  #pragma unroll
  for (int i = 0; i < 4; i++)
    #pragma unroll
    for (int j = 0; j < 4; j++) acc[i][j] = (f32x4){0.f, 0.f, 0.f, 0.f};

  stage(0, 0);
  const int nkt = Kc / 32;
  for (int kt = 0; kt < nkt; kt++) {
    const int cur = kt & 1;
    __syncthreads();                       // buf[cur] staged (vmcnt drained); prev reads done
    if (kt + 1 < nkt) stage(cur ^ 1, (kt + 1) * 32);   // overlaps with compute below
    bf16x8 af[4], bfr[4];
    #pragma unroll
    for (int i = 0; i < 4; i++) {
      int row = wr * 64 + i * 16 + r16;
      af[i] = *(const bf16x8*)(&As[cur][row * 32 + 8 * g]);
    }
    #pragma unroll
    for (int j = 0; j < 4; j++) {
      int row = wc * 64 + j * 16 + r16;
      bfr[j] = *(const bf16x8*)(&Bs[cur][row * 32 + 8 * g]);
    }
    __builtin_amdgcn_s_setprio(1);
    #pragma unroll
    for (int i = 0; i < 4; i++)
      #pragma unroll
      for (int j = 0; j < 4; j++)
        acc[i][j] = MFMA16(af[i], bfr[j], acc[i][j]);
    __builtin_amdgcn_s_setprio(0);
  }

  if (EPI == 1 && bn >= 2048) {
    // ---- pure-V block: bias add -> swizzled LDS transpose -> coalesced vt write ----
    unsigned short* T = (unsigned short*)&As[0][0];   // 128x128 bf16 = 32 KB (As+Bs)
    __syncthreads();                                  // all waves done reading As/Bs
    #pragma unroll
    for (int i = 0; i < 4; i++) {
      #pragma unroll
      for (int j = 0; j < 4; j++) {
        int col_l = wc * 64 + j * 16 + r16;
        float bv = bias[bn + col_l];
        #pragma unroll
        for (int jj = 0; jj < 4; jj++) {
          int row = wr * 64 + i * 16 + 4 * g + jj;
          // element (col,row) at byte col*256 + (row*2 ^ ((col&7)<<4))
          *(unsigned short*)((char*)T + col_l * 256 + ((row * 2) ^ ((col_l & 7) << 4))) =
              f2bf(acc[i][j][jj] + bv);
        }
      }
    }
    __syncthreads();
    int bb = bm >> 11, tk0 = bm & 2047;               // block never straddles batch
    #pragma unroll
    for (int c = 0; c < 32; c++) {
      int col_l = wave * 32 + c;
      int cv = (bn - 2048) + col_l;
      int hh = cv >> 6, d = cv & 63;
      // token-pair a=lane lives at byte (4*lane)^swz (swz flips bits>=4 only)
      unsigned v2 = *(unsigned*)((char*)T + col_l * 256 + ((lane * 4) ^ ((col_l & 7) << 4)));
      *(unsigned*)(vo + ((size_t)(bb * NHEAD + hh) * HDIM + d) * NSEQ + tk0 + lane * 2) = v2;
    }
    return;
  }

  #pragma unroll
  for (int i = 0; i < 4; i++) {
    #pragma unroll
    for (int j = 0; j < 4; j++) {
      int col = bn + wc * 64 + j * 16 + r16;
      float bv = (EPI == 2 && kz != 0) ? 0.f : bias[col];
      #pragma unroll
      for (int jj = 0; jj < 4; jj++) {
        int row = bm + wr * 64 + i * 16 + 4 * g + jj;
        float val = acc[i][j][jj] + bv;
        if (EPI == 1) {
          int cc = col & 1023;
          int hh = cc >> 6, d = cc & 63;
          int b = row >> 11, tk = row & 2047;
          size_t hb = (size_t)(b * NHEAD + hh);
          if (col < 1024) qo[(hb * NSEQ + tk) * HDIM + d] = f2bf(val * 1.4426950408889634f);
          else            ko[(hb * NSEQ + tk) * HDIM + d] = f2bf(val);
        } else if (EPI == 2) {
          size_t idx = (size_t)row * N + col;
          if (kz == 0) outf[idx] = val + resid[idx];
          else         pp[idx]   = val;
        } else {
          // tanh-approx GELU via exp2: ge = v - v/(1+exp2(2.3022*v + 0.10294*v^3))
          float vv = val * val;
          float u2 = val * (2.3022361f + 0.1029445f * vv);
          float ge = val - val / (1.0f + exp2f(u2));
          outb[(size_t)row * N + col] = f2bf(ge);
        }
      }
    }
  }
}

// ---------------- split-K merge: out[i] += pp[i] ----------------
__global__ __launch_bounds__(256)
void add_kernel(float* __restrict__ out, const float* __restrict__ pp, int n4)
{
  int i = blockIdx.x * 256 + threadIdx.x;
  int stride = gridDim.x * 256;
  for (; i < n4; i += stride) {
    float4 a = ((const float4*)out)[i];
    float4 b = ((const float4*)pp)[i];
    a.x += b.x; a.y += b.y; a.z += b.z; a.w += b.w;
    ((float4*)out)[i] = a;
  }
}

// ---------------- flash attention, swapped-operand 32x32, static-bias softmax, KV-split ----
// R13/R15-verified structure (70 us): KVBLK=32, 32 KB LDS, 4 blocks/CU.
// q(log2e-scaled),k [B,H,N,D], vt [B,H,D,N] -> y [B,N,H*D] bf16
// Static-bias softmax: P = exp2(S'-32), bias folded into QK^T MFMA C-input -> no max
// state, so KV-split partials merge by plain addition (o_sum, ssum).
__global__ __launch_bounds__(256, 4)
void attn_kernel(const unsigned short* __restrict__ q, const unsigned short* __restrict__ k,
                 const unsigned short* __restrict__ vt, unsigned short* __restrict__ y)
{
  int bid = blockIdx.x;                 // 1024 blocks
  int xcd = bid & 7, loc = bid >> 3;    // round-robin dispatch: bid%8 = XCD
  int bh  = xcd * 4 + (loc >> 5);       // 4 (b,h) pairs per XCD -> 2MB K/V, L2-resident
  int qb64 = loc & 31;                  // 32 q-chunks of 64 rows per bh
  int b = bh >> 4, h = bh & 15;
  int wave = threadIdx.x >> 6, lane = threadIdx.x & 63;
  int qt = wave >> 1, kvh = wave & 1;   // q-tile, kv-half
  int ql = lane & 31;
  int hi = lane >> 5;
  int q0 = qb64 * 64 + qt * 32;
  const int kvbase = kvh * (NSEQ / 2);
  const unsigned short* qb = q  + (size_t)bh * NSEQ * HDIM;
  const unsigned short* kb = k  + (size_t)bh * NSEQ * HDIM;
  const unsigned short* vb = vt + (size_t)bh * HDIM * NSEQ;

  // Per-half double-buffered tiles. K: [32 kv][8 chunks], chunk col ^= (row&7).
  // V: [64 d][4 chunks], chunk col ^= ((row>>1)&3). Linear dest for gll16.
  __shared__ unsigned short KL[2][2][2048];   // [kvh][dbuf]  16 KB
  __shared__ unsigned short VL[2][2][2048];   // 16 KB

  // stage tile 'it' (within this wave's half) into buffer d; the half's 2 waves
  // (qt=0,1) each issue 2 K-chunks + 2 V-chunks covering the 256-chunk tile.
  auto stage = [&](int d, int it) {
    int kv0 = kvbase + it * 32;
    #pragma unroll
    for (int i = 0; i < 2; i++) {
      int c = i * 128 + qt * 64 + lane;           // chunk 0..255
      int row = c >> 3, col = c & 7;
      int sc  = (row << 3) | (col ^ (row & 7));   // inverse-swizzled source chunk
      gll16(kb + (size_t)kv0 * HDIM + sc * 8, &KL[kvh][d][(i * 128 + qt * 64) * 8]);
    }
    #pragma unroll
    for (int i = 0; i < 2; i++) {
      int c = i * 128 + qt * 64 + lane;
      int row = c >> 2, col = c & 3;
      int scol = col ^ ((row >> 1) & 3);
      gll16(vb + (size_t)row * NSEQ + kv0 + scol * 8, &VL[kvh][d][(i * 128 + qt * 64) * 8]);
    }
  };

  // Q B-fragments: lane holds Q[q0+ql][s*16 + hi*8 .. +8]
  bf16x8 aq[4];
  #pragma unroll
  for (int s = 0; s < 4; s++)
    aq[s] = *(const bf16x8*)(qb + (size_t)(q0 + ql) * HDIM + s * 16 + hi * 8);

  float ssum = 0.f;
  f32x16 o0, o1;
  #pragma unroll
  for (int r = 0; r < 16; r++) { o0[r] = 0.f; o1[r] = 0.f; }

  stage(0, 0);
  const int nit = NSEQ / 64;            // 32 iters over this wave's kv-half
  for (int it = 0; it < nit; it++) {
    const int cur = it & 1;
    __syncthreads();                   // buf[cur] staged (vmcnt drained); prev reads done
    if (it + 1 < nit) stage(cur ^ 1, it + 1);   // overlaps with compute below
    // ---- K fragments from LDS (swizzled read) ----
    bf16x8 kf[4];
    #pragma unroll
    for (int s = 0; s < 4; s++)
      kf[s] = *(const bf16x8*)((const char*)KL[kvh][cur] +
               ql * 128 + ((((s << 1) | hi) ^ (ql & 7)) << 4));
    // ---- S^T[32k][32q] over d=64 (4 slices); C-input pre-biased to -32 ----
    f32x16 sacc;
    #pragma unroll
    for (int r = 0; r < 16; r++) sacc[r] = -32.0f;
    __builtin_amdgcn_s_setprio(1);
    #pragma unroll
    for (int s = 0; s < 4; s++)
      sacc = MFMA32(kf[s], aq[s], sacc);
    __builtin_amdgcn_s_setprio(0);
    // ---- static-bias softmax: P = exp2(S'-32), per-lane denominator only ----
    float ps = 0.f;
    #pragma unroll
    for (int r = 0; r < 16; r++) {
      sacc[r] = exp2f(sacc[r]);
      ps += sacc[r];
    }
    ssum += ps;
    // ---- V fragments from LDS (swizzled read) ----
    bf16x8 vf[2][2];
    #pragma unroll
    for (int t = 0; t < 2; t++)
      #pragma unroll
      for (int db = 0; db < 2; db++)
        vf[t][db] = *(const bf16x8*)((const char*)VL[kvh][cur] +
                     (db * 32 + ql) * 64 + ((((t << 1) | hi) ^ ((ql >> 1) & 3)) << 4));
    // ---- P -> bf16 fragments: cvt_pk pairs + permlane32_swap; PV ----
    __builtin_amdgcn_s_setprio(1);
    #pragma unroll
    for (int t = 0; t < 2; t++) {
      unsigned pk01, pk23, pk45, pk67;
      asm("v_cvt_pk_bf16_f32 %0, %1, %2" : "=v"(pk01) : "v"(sacc[8*t+0]), "v"(sacc[8*t+1]));
      asm("v_cvt_pk_bf16_f32 %0, %1, %2" : "=v"(pk23) : "v"(sacc[8*t+2]), "v"(sacc[8*t+3]));
      asm("v_cvt_pk_bf16_f32 %0, %1, %2" : "=v"(pk45) : "v"(sacc[8*t+4]), "v"(sacc[8*t+5]));
      asm("v_cvt_pk_bf16_f32 %0, %1, %2" : "=v"(pk67) : "v"(sacc[8*t+6]), "v"(sacc[8*t+7]));
      // vdst.hi <-> vsrc.lo:  pk01 -> {pk01_lo, pk45_lo} = u0,  pk45 -> {pk01_hi, pk45_hi} = u2
      asm("v_permlane32_swap_b32 %0, %1" : "+v"(pk01), "+v"(pk45));
      asm("v_permlane32_swap_b32 %0, %1" : "+v"(pk23), "+v"(pk67));
      union { unsigned u[4]; bf16x8 v; } pf;
      pf.u[0] = pk01; pf.u[1] = pk23; pf.u[2] = pk45; pf.u[3] = pk67;
      o0 = MFMA32(vf[t][0], pf.v, o0);
      o1 = MFMA32(vf[t][1], pf.v, o1);
    }
    __builtin_amdgcn_s_setprio(0);
  }

  // ---- merge kv-half partners: plain addition (no max state) ----
  __syncthreads();                      // all waves done with KL/VL
  float* OM = (float*)&KL[0][0][0];     // 4096 floats: [r 0..31][128 lanes], conflict-free
  float* SM = (float*)&VL[0][0][0];     // 128 floats
  if (kvh == 1) {
    #pragma unroll
    for (int r = 0; r < 16; r++) {
      OM[r * 128 + qt * 64 + lane]        = o0[r];
      OM[(16 + r) * 128 + qt * 64 + lane] = o1[r];
    }
    SM[qt * 64 + lane] = ssum;
  }
  __syncthreads();
  if (kvh == 0) {
    float st = ssum + SM[qt * 64 + lane];
    st += __shfl_xor(st, 32);           // combine lane k-subset halves
    float inv = 1.0f / st;
    #pragma unroll
    for (int r = 0; r < 16; r++) {
      o0[r] += OM[r * 128 + qt * 64 + lane];
      o1[r] += OM[(16 + r) * 128 + qt * 64 + lane];
    }
    // O^T: lane col q=ql, rows d = db*32 + (r&3)+8*(r>>2)+4*hi
    unsigned short* yr = y + ((size_t)(b * NSEQ + q0 + ql)) * CDIM + h * HDIM;
    #pragma unroll
    for (int db = 0; db < 2; db++) {
      const f32x16& oo = db ? o1 : o0;
      #pragma unroll
      for (int rq = 0; rq < 4; rq++) {
        us4 w;
        w.x = f2bf(oo[4*rq+0] * inv);
        w.y = f2bf(oo[4*rq+1] * inv);
        w.z = f2bf(oo[4*rq+2] * inv);
        w.w = f2bf(oo[4*rq+3] * inv);
        *(us4*)(yr + db * 32 + rq * 8 + hi * 4) = w;
      }
    }
  }
}

extern "C" void kernel_launch(void* const* d_in, const int* in_sizes, int n_in,
                              void* d_out, int out_size, void* d_ws, size_t ws_size,
                              hipStream_t stream)
{
  const float* x      = (const float*)d_in[0];
  const float* ln1_g  = (const float*)d_in[1];
  const float* ln1_b  = (const float*)d_in[2];
  const float* qkv_w  = (const float*)d_in[3];
  const float* qkv_b  = (const float*)d_in[4];
  const float* proj_w = (const float*)d_in[5];
  const float* proj_b = (const float*)d_in[6];
  const float* ln2_g  = (const float*)d_in[7];
  const float* ln2_b  = (const float*)d_in[8];
  const float* fc1_w  = (const float*)d_in[9];
  const float* fc1_b  = (const float*)d_in[10];
  const float* fc2_w  = (const float*)d_in[11];
  const float* fc2_b  = (const float*)d_in[12];
  float* out = (float*)d_out;

  char* p = (char*)d_ws;
  size_t off = 0;
  auto alloc = [&](size_t bytes) -> void* {
    void* r = p + off; off += (bytes + 255) & ~(size_t)255; return r;
  };
  unsigned short* wt_qkv  = (unsigned short*)alloc((size_t)3072 * 1024 * 2);
  unsigned short* wt_proj = (unsigned short*)alloc((size_t)1024 * 1024 * 2);
  unsigned short* wt_fc1  = (unsigned short*)alloc((size_t)4096 * 1024 * 2);
  unsigned short* wt_fc2  = (unsigned short*)alloc((size_t)1024 * 4096 * 2);
  unsigned short* h1  = (unsigned short*)alloc((size_t)TROWS * CDIM * 2);
  unsigned short* qb  = (unsigned short*)alloc((size_t)TROWS * CDIM * 2);
  unsigned short* kb  = (unsigned short*)alloc((size_t)TROWS * CDIM * 2);
  unsigned short* vtb = (unsigned short*)alloc((size_t)TROWS * CDIM * 2);
  unsigned short* yb  = (unsigned short*)alloc((size_t)TROWS * CDIM * 2);
  float*          x1  = (float*)alloc((size_t)TROWS * CDIM * 4);
  unsigned short* h2  = (unsigned short*)alloc((size_t)TROWS * CDIM * 2);
  unsigned short* g1  = (unsigned short*)alloc((size_t)TROWS * MLPDIM * 2);
  // split-K partial (proj & FC2, sequential uses): aliases qb+kb (dead after attention)
  float* pp = (float*)qb;

  dim3 blk(256);
  // fused weight transpose + bf16 (single launch, 12288 tiles)
  wt_all_kernel<<<dim3(12288), blk, 0, stream>>>(
      qkv_w, wt_qkv, proj_w, wt_proj, fc1_w, wt_fc1, fc2_w, wt_fc2);
  // LN1
  ln_bf16_kernel<<<TROWS, blk, 0, stream>>>(x, ln1_g, ln1_b, h1);
  // QKV (q pre-scaled by log2e): nbx=24, nby=32, grid 768
  gemm_bt<1><<<dim3(768), blk, 0, stream>>>(
      h1, wt_qkv, qkv_b, 1024, 1024, 24, 32,
      nullptr, nullptr, nullptr, nullptr, qb, kb, vtb);
  // attention (flat 1024-block grid, XCD-clustered, KV-split, KVBLK=32)
  attn_kernel<<<dim3(1024), blk, 0, stream>>>(qb, kb, vtb, yb);
  // proj + residual -> x1 (fp32), split-K=2: nbx=8, nby=32, grid 512 (kz 0/1)
  gemm_bt<2><<<dim3(512), blk, 0, stream>>>(
      yb, wt_proj, proj_b, 1024, 512, 8, 32,
      x1, nullptr, x, pp, nullptr, nullptr, nullptr);
  // LN2 fused with proj split-K merge: x1 += pp; h2 = LN(x1)
  ln_add_bf16_kernel<<<TROWS, blk, 0, stream>>>(x1, pp, ln2_g, ln2_b, h2);
  // FC1 + tanh-GELU -> g1 (bf16): nbx=32, nby=32, grid 1024
  gemm_bt<3><<<dim3(1024), blk, 0, stream>>>(
      h2, wt_fc1, fc1_b, 1024, 1024, 32, 32,
      nullptr, g1, nullptr, nullptr, nullptr, nullptr, nullptr);
  // FC2 + residual -> out (fp32), split-K=2: nbx=8, nby=32, grid 512 (kz 0/1)
  gemm_bt<2><<<dim3(512), blk, 0, stream>>>(
      g1, wt_fc2, fc2_b, 4096, 2048, 8, 32,
      out, nullptr, x1, pp, nullptr, nullptr, nullptr);
  // merge split-K partial: out += pp (4M floats = 1M float4)
  add_kernel<<<dim3(2048), blk, 0, stream>>>(out, pp, TROWS * CDIM / 4);
}

// Round 18
// 274.823 us; speedup vs baseline: 1.0449x; 1.0046x over previous
//
#include <hip/hip_runtime.h>
#include <hip/hip_bf16.h>

#define CDIM   1024
#define NSEQ   2048
#define NHEAD  16
#define HDIM   64
#define MLPDIM 4096
#define TROWS  4096   // B*N = 2*2048

typedef __attribute__((ext_vector_type(8)))  __bf16 bf16x8;
typedef __attribute__((ext_vector_type(4)))  float  f32x4;
typedef __attribute__((ext_vector_type(16))) float  f32x16;
typedef __attribute__((ext_vector_type(4)))  unsigned short us4;

static __device__ __forceinline__ unsigned short f2bf(float f) {
  unsigned int u = __float_as_uint(f);
  u += 0x7fffu + ((u >> 16) & 1u);      // round-to-nearest-even
  return (unsigned short)(u >> 16);
}

#define MFMA16(a, b, c) __builtin_amdgcn_mfma_f32_16x16x32_bf16(a, b, c, 0, 0, 0)
#define MFMA32(a, b, c) __builtin_amdgcn_mfma_f32_32x32x16_bf16(a, b, c, 0, 0, 0)

// async global->LDS, 16B per lane; LDS dest must be wave-uniform (linear layout)
static __device__ __forceinline__ void gll16(const unsigned short* g, unsigned short* l) {
  __builtin_amdgcn_global_load_lds(
      (const __attribute__((address_space(1))) unsigned int*)g,
      (__attribute__((address_space(3))) unsigned int*)l, 16, 0, 0);
}

// ---------------- LayerNorm: fp32 in -> bf16 out ----------------
__global__ __launch_bounds__(256)
void ln_bf16_kernel(const float* __restrict__ x,
                    const float* __restrict__ gam,
                    const float* __restrict__ bet,
                    unsigned short* __restrict__ out)
{
  int row = blockIdx.x;
  int t = threadIdx.x;
  const float4* xr = (const float4*)(x + (size_t)row * CDIM);
  float4 v = xr[t];
  float s  = v.x + v.y + v.z + v.w;
  float s2 = v.x*v.x + v.y*v.y + v.z*v.z + v.w*v.w;
  #pragma unroll
  for (int off = 32; off > 0; off >>= 1) {
    s  += __shfl_down(s, off);
    s2 += __shfl_down(s2, off);
  }
  __shared__ float rs[4], rs2[4];
  int wave = t >> 6, lane = t & 63;
  if (lane == 0) { rs[wave] = s; rs2[wave] = s2; }
  __syncthreads();
  float fs  = rs[0] + rs[1] + rs[2] + rs[3];
  float fs2 = rs2[0] + rs2[1] + rs2[2] + rs2[3];
  float mu   = fs * (1.0f / CDIM);
  float var  = fs2 * (1.0f / CDIM) - mu * mu;
  float rstd = rsqrtf(var + 1e-5f);
  float4 gg = ((const float4*)gam)[t];
  float4 bb = ((const float4*)bet)[t];
  us4 o;
  o.x = f2bf((v.x - mu) * rstd * gg.x + bb.x);
  o.y = f2bf((v.y - mu) * rstd * gg.y + bb.y);
  o.z = f2bf((v.z - mu) * rstd * gg.z + bb.z);
  o.w = f2bf((v.w - mu) * rstd * gg.w + bb.w);
  ((us4*)(out + (size_t)row * CDIM))[t] = o;
}

// ------------- LayerNorm fused with split-K merge: v = x+pp; x=v; out=LN(v) -------------
__global__ __launch_bounds__(256)
void ln_add_bf16_kernel(float* __restrict__ x, const float* __restrict__ pp,
                        const float* __restrict__ gam, const float* __restrict__ bet,
                        unsigned short* __restrict__ out)
{
  int row = blockIdx.x;
  int t = threadIdx.x;
  float4* xr = (float4*)(x + (size_t)row * CDIM);
  const float4* pr = (const float4*)(pp + (size_t)row * CDIM);
  float4 v = xr[t];
  float4 q = pr[t];
  v.x += q.x; v.y += q.y; v.z += q.z; v.w += q.w;
  xr[t] = v;                               // merged residual written back for FC2
  float s  = v.x + v.y + v.z + v.w;
  float s2 = v.x*v.x + v.y*v.y + v.z*v.z + v.w*v.w;
  #pragma unroll
  for (int off = 32; off > 0; off >>= 1) {
    s  += __shfl_down(s, off);
    s2 += __shfl_down(s2, off);
  }
  __shared__ float rs[4], rs2[4];
  int wave = t >> 6, lane = t & 63;
  if (lane == 0) { rs[wave] = s; rs2[wave] = s2; }
  __syncthreads();
  float fs  = rs[0] + rs[1] + rs[2] + rs[3];
  float fs2 = rs2[0] + rs2[1] + rs2[2] + rs2[3];
  float mu   = fs * (1.0f / CDIM);
  float var  = fs2 * (1.0f / CDIM) - mu * mu;
  float rstd = rsqrtf(var + 1e-5f);
  float4 gg = ((const float4*)gam)[t];
  float4 bb = ((const float4*)bet)[t];
  us4 o;
  o.x = f2bf((v.x - mu) * rstd * gg.x + bb.x);
  o.y = f2bf((v.y - mu) * rstd * gg.y + bb.y);
  o.z = f2bf((v.z - mu) * rstd * gg.z + bb.z);
  o.w = f2bf((v.w - mu) * rstd * gg.w + bb.w);
  ((us4*)(out + (size_t)row * CDIM))[t] = o;
}

// ------------- fused weight transpose + fp32->bf16 for all four weights -------------
// flat grid of 32x32 tiles: [0,3072) qkv  [3072,4096) proj  [4096,8192) fc1  [8192,12288) fc2
__global__ __launch_bounds__(256)
void wt_all_kernel(const float* __restrict__ W0, unsigned short* __restrict__ T0,
                   const float* __restrict__ W1, unsigned short* __restrict__ T1,
                   const float* __restrict__ W2, unsigned short* __restrict__ T2,
                   const float* __restrict__ W3, unsigned short* __restrict__ T3)
{
  int id = blockIdx.x;
  const float* W; unsigned short* Wt; int K, N, nx;
  if (id < 3072)      { W = W0; Wt = T0; K = 1024; N = 3072; nx = 96; }
  else if (id < 4096) { W = W1; Wt = T1; K = 1024; N = 1024; nx = 32; id -= 3072; }
  else if (id < 8192) { W = W2; Wt = T2; K = 1024; N = 4096; nx = 128; id -= 4096; }
  else                { W = W3; Wt = T3; K = 4096; N = 1024; nx = 32; id -= 8192; }
  int n0 = (id % nx) * 32, k0 = (id / nx) * 32;

  __shared__ float tile[32][33];
  int t = threadIdx.x;
  int r = t >> 3, c4 = (t & 7) << 2;
  float4 v = *(const float4*)(W + (size_t)(k0 + r) * N + n0 + c4);
  tile[r][c4 + 0] = v.x; tile[r][c4 + 1] = v.y;
  tile[r][c4 + 2] = v.z; tile[r][c4 + 3] = v.w;
  __syncthreads();
  us4 o;
  o.x = f2bf(tile[c4 + 0][r]);
  o.y = f2bf(tile[c4 + 1][r]);
  o.z = f2bf(tile[c4 + 2][r]);
  o.w = f2bf(tile[c4 + 3][r]);
  *(us4*)(Wt + (size_t)(n0 + r) * K + k0 + c4) = o;
}

// ---------------- GEMM: C = A * Bt^T (+bias), fused epilogues, XCD-swizzled, split-K ----
// 2-buffer LDS dbuf (R11-verified): barrier -> issue stage(kt+1) -> compute(kt).
// EPI 1: qkv split (V via swizzled-LDS transpose).  EPI 2: split-K.  EPI 3: tanh-GELU.
template<int EPI>
__global__ __launch_bounds__(256, 4)
void gemm_bt(const unsigned short* __restrict__ A, const unsigned short* __restrict__ Bt,
             const float* __restrict__ bias, int Kstride, int Kc, int nbx, int nby,
             float* __restrict__ outf, unsigned short* __restrict__ outb,
             const float* __restrict__ resid, float* __restrict__ pp,
             unsigned short* __restrict__ qo, unsigned short* __restrict__ ko,
             unsigned short* __restrict__ vo)
{
  __shared__ unsigned short As[2][128 * 32];   // linear [128][32] (global_load_lds order)
  __shared__ unsigned short Bs[2][128 * 32];
  const int tid  = threadIdx.x;
  const int lane = tid & 63;
  const int wave = tid >> 6;
  const int wr = wave >> 1, wc = wave & 1;      // 2x2 waves, 64x64 each
  const int g = lane >> 4, r16 = lane & 15;

  const int nwg = gridDim.x;
  const int orig = ((int)blockIdx.x & 7) * (nwg >> 3) + ((int)blockIdx.x >> 3);
  const int bx = orig % nbx;
  const int t2 = orig / nbx;
  const int by = t2 % nby;
  const int kz = t2 / nby;
  const int bm = by * 128, bn = bx * 128;
  const int kbase = kz * Kc;
  const int N = nbx * 128;

  // stage K-tile (kbase + k0) into buffer d
  auto stage = [&](int d, int k0) {
    #pragma unroll
    for (int c = 0; c < 2; c++) {
      int o   = (c * 256 + tid) << 3;          // this lane's element offset in 128x32 tile
      int row = o >> 5;
      int col = o & 31;
      int ub  = (c * 256 + (tid & ~63)) << 3;  // wave-uniform LDS element base
      gll16(A  + (size_t)(bm + row) * Kstride + kbase + k0 + col, &As[d][ub]);
      gll16(Bt + (size_t)(bn + row) * Kstride + kbase + k0 + col, &Bs[d][ub]);
    }
  };

  f32x4 acc[4][4];
  #pragma unroll
  for (int i = 0; i < 4; i++)
    #pragma unroll
    for (int j = 0; j < 4; j++) acc[i][j] = (f32x4){0.f, 0.f, 0.f, 0.f};

  stage(0, 0);
  const int nkt = Kc / 32;
  for (int kt = 0; kt < nkt; kt++) {
    const int cur = kt & 1;
    __syncthreads();                       // buf[cur] staged (vmcnt drained); prev reads done
    if (kt + 1 < nkt) stage(cur ^ 1, (kt + 1) * 32);   // overlaps with compute below
    bf16x8 af[4], bfr[4];
    #pragma unroll
    for (int i = 0; i < 4; i++) {
      int row = wr * 64 + i * 16 + r16;
      af[i] = *(const bf16x8*)(&As[cur][row * 32 + 8 * g]);
    }
    #pragma unroll
    for (int j = 0; j < 4; j++) {
      int row = wc * 64 + j * 16 + r16;
      bfr[j] = *(const bf16x8*)(&Bs[cur][row * 32 + 8 * g]);
    }
    __builtin_amdgcn_s_setprio(1);
    #pragma unroll
    for (int i = 0; i < 4; i++)
      #pragma unroll
      for (int j = 0; j < 4; j++)
        acc[i][j] = MFMA16(af[i], bfr[j], acc[i][j]);
    __builtin_amdgcn_s_setprio(0);
  }

  if (EPI == 1 && bn >= 2048) {
    // ---- pure-V block: bias add -> swizzled LDS transpose -> coalesced vt write ----
    unsigned short* T = (unsigned short*)&As[0][0];   // 128x128 bf16 = 32 KB (As+Bs)
    __syncthreads();                                  // all waves done reading As/Bs
    #pragma unroll
    for (int i = 0; i < 4; i++) {
      #pragma unroll
      for (int j = 0; j < 4; j++) {
        int col_l = wc * 64 + j * 16 + r16;
        float bv = bias[bn + col_l];
        #pragma unroll
        for (int jj = 0; jj < 4; jj++) {
          int row = wr * 64 + i * 16 + 4 * g + jj;
          *(unsigned short*)((char*)T + col_l * 256 + ((row * 2) ^ ((col_l & 7) << 4))) =
              f2bf(acc[i][j][jj] + bv);
        }
      }
    }
    __syncthreads();
    int bb = bm >> 11, tk0 = bm & 2047;               // block never straddles batch
    #pragma unroll
    for (int c = 0; c < 32; c++) {
      int col_l = wave * 32 + c;
      int cv = (bn - 2048) + col_l;
      int hh = cv >> 6, d = cv & 63;
      unsigned v2 = *(unsigned*)((char*)T + col_l * 256 + ((lane * 4) ^ ((col_l & 7) << 4)));
      *(unsigned*)(vo + ((size_t)(bb * NHEAD + hh) * HDIM + d) * NSEQ + tk0 + lane * 2) = v2;
    }
    return;
  }

  #pragma unroll
  for (int i = 0; i < 4; i++) {
    #pragma unroll
    for (int j = 0; j < 4; j++) {
      int col = bn + wc * 64 + j * 16 + r16;
      float bv = (EPI == 2 && kz != 0) ? 0.f : bias[col];
      #pragma unroll
      for (int jj = 0; jj < 4; jj++) {
        int row = bm + wr * 64 + i * 16 + 4 * g + jj;
        float val = acc[i][j][jj] + bv;
        if (EPI == 1) {
          int cc = col & 1023;
          int hh = cc >> 6, d = cc & 63;
          int b = row >> 11, tk = row & 2047;
          size_t hb = (size_t)(b * NHEAD + hh);
          if (col < 1024) qo[(hb * NSEQ + tk) * HDIM + d] = f2bf(val * 1.4426950408889634f);
          else            ko[(hb * NSEQ + tk) * HDIM + d] = f2bf(val);
        } else if (EPI == 2) {
          size_t idx = (size_t)row * N + col;
          if (kz == 0) outf[idx] = val + resid[idx];
          else         pp[idx]   = val;
        } else {
          float vv = val * val;
          float u2 = val * (2.3022361f + 0.1029445f * vv);
          float ge = val - val / (1.0f + exp2f(u2));
          outb[(size_t)row * N + col] = f2bf(ge);
        }
      }
    }
  }
}

// ======== FC1: 256x256 tile, BK=32, 8 waves, counted-vmcnt raw-barrier pipeline ========
// T3+T4 mechanism: no vmcnt(0) drain in the main loop. Per K-tile:
//   vmcnt(4) [stage(kt) landed; stage(kt+1)'s 4 loads stay in flight] -> s_barrier ->
//   12 swizzled ds_read_b128 -> lgkmcnt(0)+fence -> s_barrier ->
//   issue stage(kt+2) into just-read buffer -> 32 MFMA (setprio).
// Hazards: vmcnt FIFO retires oldest-first (m135); buffer overwritten at kt+2 was
// read-complete by ALL waves before barrier #2; uniform control flow keeps barriers matched.
// LDS chunk swizzle (both sides, rule #21): 16B chunk cc at row r stored at cc^(r&3);
// inverse applied to gll16 SOURCE (linear dest); ds_read XORs the same.
__global__ __launch_bounds__(512, 1)
void gemm_fc1(const unsigned short* __restrict__ A, const unsigned short* __restrict__ Bt,
              const float* __restrict__ bias, unsigned short* __restrict__ outb)
{
  __shared__ unsigned short As[2][256 * 32];   // 32 KB
  __shared__ unsigned short Bs[2][256 * 32];   // 32 KB
  const int tid  = threadIdx.x;
  const int lane = tid & 63;
  const int wave = tid >> 6;
  const int wr = wave >> 2, wc = wave & 3;      // 2x4 waves, 128 rows x 64 cols each
  const int g = lane >> 4, r16 = lane & 15;
  const int K = 1024, N = MLPDIM;

  const int nwg = gridDim.x;                    // 256
  const int orig = ((int)blockIdx.x & 7) * (nwg >> 3) + ((int)blockIdx.x >> 3);
  const int bx = orig & 15, by = orig >> 4;
  const int bm = by * 256, bn = bx * 256;

  // stage K-tile kt into buffer d: 2 A-chunks + 2 B-chunks per thread (4 vmem ops)
  auto stage = [&](int d, int kt) {
    int k0 = kt * 32;
    #pragma unroll
    for (int l = 0; l < 2; l++) {
      int p   = l * 512 + tid;                 // dest chunk 0..1023 (row p>>2, cc p&3)
      int row = p >> 2, cc = p & 3;
      int scc = cc ^ (row & 3);                // inverse swizzle at source
      int ub  = (l * 512 + (tid & ~63)) << 3;  // wave-uniform LDS element base
      gll16(A  + (size_t)(bm + row) * K + k0 + (scc << 3), &As[d][ub]);
      gll16(Bt + (size_t)(bn + row) * K + k0 + (scc << 3), &Bs[d][ub]);
    }
  };

  f32x4 acc[8][4];
  #pragma unroll
  for (int i = 0; i < 8; i++)
    #pragma unroll
    for (int j = 0; j < 4; j++) acc[i][j] = (f32x4){0.f, 0.f, 0.f, 0.f};

  stage(0, 0);
  stage(1, 1);
  const int nkt = K / 32;                      // 32
  for (int kt = 0; kt < nkt; kt++) {
    const int cur = kt & 1;
    if (kt + 1 < nkt) asm volatile("s_waitcnt vmcnt(4)" ::: "memory");  // stage(kt) landed
    else              asm volatile("s_waitcnt vmcnt(0)" ::: "memory");  // last: drain
    __builtin_amdgcn_s_barrier();              // buf[cur] valid across all waves
    asm volatile("" ::: "memory");
    bf16x8 af[8], bfr[4];
    #pragma unroll
    for (int i = 0; i < 8; i++) {
      int row = wr * 128 + i * 16 + r16;
      af[i] = *(const bf16x8*)((const char*)&As[cur][0] + row * 64 + ((g ^ (row & 3)) << 4));
    }
    #pragma unroll
    for (int j = 0; j < 4; j++) {
      int row = wc * 64 + j * 16 + r16;
      bfr[j] = *(const bf16x8*)((const char*)&Bs[cur][0] + row * 64 + ((g ^ (row & 3)) << 4));
    }
    asm volatile("s_waitcnt lgkmcnt(0)" ::: "memory");   // all my reads of buf[cur] done
    __builtin_amdgcn_s_barrier();              // all waves' reads done -> safe to overwrite
    asm volatile("" ::: "memory");
    if (kt + 2 < nkt) stage(cur, kt + 2);      // overlaps MFMAs + next iteration
    __builtin_amdgcn_s_setprio(1);
    #pragma unroll
    for (int i = 0; i < 8; i++)
      #pragma unroll
      for (int j = 0; j < 4; j++)
        acc[i][j] = MFMA16(af[i], bfr[j], acc[i][j]);
    __builtin_amdgcn_s_setprio(0);
  }

  #pragma unroll
  for (int i = 0; i < 8; i++) {
    #pragma unroll
    for (int j = 0; j < 4; j++) {
      int col = bn + wc * 64 + j * 16 + r16;
      float bv = bias[col];
      #pragma unroll
      for (int jj = 0; jj < 4; jj++) {
        int row = bm + wr * 128 + i * 16 + 4 * g + jj;
        float val = acc[i][j][jj] + bv;
        // tanh-approx GELU via exp2
        float vv = val * val;
        float u2 = val * (2.3022361f + 0.1029445f * vv);
        float ge = val - val / (1.0f + exp2f(u2));
        outb[(size_t)row * N + col] = f2bf(ge);
      }
    }
  }
}

// ---------------- split-K merge: out[i] += pp[i] ----------------
__global__ __launch_bounds__(256)
void add_kernel(float* __restrict__ out, const float* __restrict__ pp, int n4)
{
  int i = blockIdx.x * 256 + threadIdx.x;
  int stride = gridDim.x * 256;
  for (; i < n4; i += stride) {
    float4 a = ((const float4*)out)[i];
    float4 b = ((const float4*)pp)[i];
    a.x += b.x; a.y += b.y; a.z += b.z; a.w += b.w;
    ((float4*)out)[i] = a;
  }
}

// ---------------- flash attention, swapped-operand 32x32, static-bias softmax, KV-split ----
// R13/R15-verified structure (70 us): KVBLK=32, 32 KB LDS, 4 blocks/CU.
__global__ __launch_bounds__(256, 4)
void attn_kernel(const unsigned short* __restrict__ q, const unsigned short* __restrict__ k,
                 const unsigned short* __restrict__ vt, unsigned short* __restrict__ y)
{
  int bid = blockIdx.x;                 // 1024 blocks
  int xcd = bid & 7, loc = bid >> 3;    // round-robin dispatch: bid%8 = XCD
  int bh  = xcd * 4 + (loc >> 5);       // 4 (b,h) pairs per XCD -> 2MB K/V, L2-resident
  int qb64 = loc & 31;                  // 32 q-chunks of 64 rows per bh
  int b = bh >> 4, h = bh & 15;
  int wave = threadIdx.x >> 6, lane = threadIdx.x & 63;
  int qt = wave >> 1, kvh = wave & 1;   // q-tile, kv-half
  int ql = lane & 31;
  int hi = lane >> 5;
  int q0 = qb64 * 64 + qt * 32;
  const int kvbase = kvh * (NSEQ / 2);
  const unsigned short* qb = q  + (size_t)bh * NSEQ * HDIM;
  const unsigned short* kb = k  + (size_t)bh * NSEQ * HDIM;
  const unsigned short* vb = vt + (size_t)bh * HDIM * NSEQ;

  __shared__ unsigned short KL[2][2][2048];   // [kvh][dbuf]  16 KB
  __shared__ unsigned short VL[2][2][2048];   // 16 KB

  auto stage = [&](int d, int it) {
    int kv0 = kvbase + it * 32;
    #pragma unroll
    for (int i = 0; i < 2; i++) {
      int c = i * 128 + qt * 64 + lane;           // chunk 0..255
      int row = c >> 3, col = c & 7;
      int sc  = (row << 3) | (col ^ (row & 7));   // inverse-swizzled source chunk
      gll16(kb + (size_t)kv0 * HDIM + sc * 8, &KL[kvh][d][(i * 128 + qt * 64) * 8]);
    }
    #pragma unroll
    for (int i = 0; i < 2; i++) {
      int c = i * 128 + qt * 64 + lane;
      int row = c >> 2, col = c & 3;
      int scol = col ^ ((row >> 1) & 3);
      gll16(vb + (size_t)row * NSEQ + kv0 + scol * 8, &VL[kvh][d][(i * 128 + qt * 64) * 8]);
    }
  };

  bf16x8 aq[4];
  #pragma unroll
  for (int s = 0; s < 4; s++)
    aq[s] = *(const bf16x8*)(qb + (size_t)(q0 + ql) * HDIM + s * 16 + hi * 8);

  float ssum = 0.f;
  f32x16 o0, o1;
  #pragma unroll
  for (int r = 0; r < 16; r++) { o0[r] = 0.f; o1[r] = 0.f; }

  stage(0, 0);
  const int nit = NSEQ / 64;            // 32 iters over this wave's kv-half
  for (int it = 0; it < nit; it++) {
    const int cur = it & 1;
    __syncthreads();                   // buf[cur] staged (vmcnt drained); prev reads done
    if (it + 1 < nit) stage(cur ^ 1, it + 1);   // overlaps with compute below
    bf16x8 kf[4];
    #pragma unroll
    for (int s = 0; s < 4; s++)
      kf[s] = *(const bf16x8*)((const char*)KL[kvh][cur] +
               ql * 128 + ((((s << 1) | hi) ^ (ql & 7)) << 4));
    f32x16 sacc;
    #pragma unroll
    for (int r = 0; r < 16; r++) sacc[r] = -32.0f;
    __builtin_amdgcn_s_setprio(1);
    #pragma unroll
    for (int s = 0; s < 4; s++)
      sacc = MFMA32(kf[s], aq[s], sacc);
    __builtin_amdgcn_s_setprio(0);
    float ps = 0.f;
    #pragma unroll
    for (int r = 0; r < 16; r++) {
      sacc[r] = exp2f(sacc[r]);
      ps += sacc[r];
    }
    ssum += ps;
    bf16x8 vf[2][2];
    #pragma unroll
    for (int t = 0; t < 2; t++)
      #pragma unroll
      for (int db = 0; db < 2; db++)
        vf[t][db] = *(const bf16x8*)((const char*)VL[kvh][cur] +
                     (db * 32 + ql) * 64 + ((((t << 1) | hi) ^ ((ql >> 1) & 3)) << 4));
    __builtin_amdgcn_s_setprio(1);
    #pragma unroll
    for (int t = 0; t < 2; t++) {
      unsigned pk01, pk23, pk45, pk67;
      asm("v_cvt_pk_bf16_f32 %0, %1, %2" : "=v"(pk01) : "v"(sacc[8*t+0]), "v"(sacc[8*t+1]));
      asm("v_cvt_pk_bf16_f32 %0, %1, %2" : "=v"(pk23) : "v"(sacc[8*t+2]), "v"(sacc[8*t+3]));
      asm("v_cvt_pk_bf16_f32 %0, %1, %2" : "=v"(pk45) : "v"(sacc[8*t+4]), "v"(sacc[8*t+5]));
      asm("v_cvt_pk_bf16_f32 %0, %1, %2" : "=v"(pk67) : "v"(sacc[8*t+6]), "v"(sacc[8*t+7]));
      asm("v_permlane32_swap_b32 %0, %1" : "+v"(pk01), "+v"(pk45));
      asm("v_permlane32_swap_b32 %0, %1" : "+v"(pk23), "+v"(pk67));
      union { unsigned u[4]; bf16x8 v; } pf;
      pf.u[0] = pk01; pf.u[1] = pk23; pf.u[2] = pk45; pf.u[3] = pk67;
      o0 = MFMA32(vf[t][0], pf.v, o0);
      o1 = MFMA32(vf[t][1], pf.v, o1);
    }
    __builtin_amdgcn_s_setprio(0);
  }

  __syncthreads();                      // all waves done with KL/VL
  float* OM = (float*)&KL[0][0][0];     // 4096 floats: [r 0..31][128 lanes], conflict-free
  float* SM = (float*)&VL[0][0][0];     // 128 floats
  if (kvh == 1) {
    #pragma unroll
    for (int r = 0; r < 16; r++) {
      OM[r * 128 + qt * 64 + lane]        = o0[r];
      OM[(16 + r) * 128 + qt * 64 + lane] = o1[r];
    }
    SM[qt * 64 + lane] = ssum;
  }
  __syncthreads();
  if (kvh == 0) {
    float st = ssum + SM[qt * 64 + lane];
    st += __shfl_xor(st, 32);           // combine lane k-subset halves
    float inv = 1.0f / st;
    #pragma unroll
    for (int r = 0; r < 16; r++) {
      o0[r] += OM[r * 128 + qt * 64 + lane];
      o1[r] += OM[(16 + r) * 128 + qt * 64 + lane];
    }
    unsigned short* yr = y + ((size_t)(b * NSEQ + q0 + ql)) * CDIM + h * HDIM;
    #pragma unroll
    for (int db = 0; db < 2; db++) {
      const f32x16& oo = db ? o1 : o0;
      #pragma unroll
      for (int rq = 0; rq < 4; rq++) {
        us4 w;
        w.x = f2bf(oo[4*rq+0] * inv);
        w.y = f2bf(oo[4*rq+1] * inv);
        w.z = f2bf(oo[4*rq+2] * inv);
        w.w = f2bf(oo[4*rq+3] * inv);
        *(us4*)(yr + db * 32 + rq * 8 + hi * 4) = w;
      }
    }
  }
}

extern "C" void kernel_launch(void* const* d_in, const int* in_sizes, int n_in,
                              void* d_out, int out_size, void* d_ws, size_t ws_size,
                              hipStream_t stream)
{
  const float* x      = (const float*)d_in[0];
  const float* ln1_g  = (const float*)d_in[1];
  const float* ln1_b  = (const float*)d_in[2];
  const float* qkv_w  = (const float*)d_in[3];
  const float* qkv_b  = (const float*)d_in[4];
  const float* proj_w = (const float*)d_in[5];
  const float* proj_b = (const float*)d_in[6];
  const float* ln2_g  = (const float*)d_in[7];
  const float* ln2_b  = (const float*)d_in[8];
  const float* fc1_w  = (const float*)d_in[9];
  const float* fc1_b  = (const float*)d_in[10];
  const float* fc2_w  = (const float*)d_in[11];
  const float* fc2_b  = (const float*)d_in[12];
  float* out = (float*)d_out;

  char* p = (char*)d_ws;
  size_t off = 0;
  auto alloc = [&](size_t bytes) -> void* {
    void* r = p + off; off += (bytes + 255) & ~(size_t)255; return r;
  };
  unsigned short* wt_qkv  = (unsigned short*)alloc((size_t)3072 * 1024 * 2);
  unsigned short* wt_proj = (unsigned short*)alloc((size_t)1024 * 1024 * 2);
  unsigned short* wt_fc1  = (unsigned short*)alloc((size_t)4096 * 1024 * 2);
  unsigned short* wt_fc2  = (unsigned short*)alloc((size_t)1024 * 4096 * 2);
  unsigned short* h1  = (unsigned short*)alloc((size_t)TROWS * CDIM * 2);
  unsigned short* qb  = (unsigned short*)alloc((size_t)TROWS * CDIM * 2);
  unsigned short* kb  = (unsigned short*)alloc((size_t)TROWS * CDIM * 2);
  unsigned short* vtb = (unsigned short*)alloc((size_t)TROWS * CDIM * 2);
  unsigned short* yb  = (unsigned short*)alloc((size_t)TROWS * CDIM * 2);
  float*          x1  = (float*)alloc((size_t)TROWS * CDIM * 4);
  unsigned short* h2  = (unsigned short*)alloc((size_t)TROWS * CDIM * 2);
  unsigned short* g1  = (unsigned short*)alloc((size_t)TROWS * MLPDIM * 2);
  // split-K partial (proj & FC2, sequential uses): aliases qb+kb (dead after attention)
  float* pp = (float*)qb;

  dim3 blk(256);
  // fused weight transpose + bf16 (single launch, 12288 tiles)
  wt_all_kernel<<<dim3(12288), blk, 0, stream>>>(
      qkv_w, wt_qkv, proj_w, wt_proj, fc1_w, wt_fc1, fc2_w, wt_fc2);
  // LN1
  ln_bf16_kernel<<<TROWS, blk, 0, stream>>>(x, ln1_g, ln1_b, h1);
  // QKV (q pre-scaled by log2e): nbx=24, nby=32, grid 768
  gemm_bt<1><<<dim3(768), blk, 0, stream>>>(
      h1, wt_qkv, qkv_b, 1024, 1024, 24, 32,
      nullptr, nullptr, nullptr, nullptr, qb, kb, vtb);
  // attention (flat 1024-block grid, XCD-clustered, KV-split, KVBLK=32)
  attn_kernel<<<dim3(1024), blk, 0, stream>>>(qb, kb, vtb, yb);
  // proj + residual -> x1 (fp32), split-K=2: nbx=8, nby=32, grid 512 (kz 0/1)
  gemm_bt<2><<<dim3(512), blk, 0, stream>>>(
      yb, wt_proj, proj_b, 1024, 512, 8, 32,
      x1, nullptr, x, pp, nullptr, nullptr, nullptr);
  // LN2 fused with proj split-K merge: x1 += pp; h2 = LN(x1)
  ln_add_bf16_kernel<<<TROWS, blk, 0, stream>>>(x1, pp, ln2_g, ln2_b, h2);
  // FC1 + tanh-GELU -> g1 (bf16): 256^2 tiles, counted-vmcnt pipeline, grid 256 x 512thr
  gemm_fc1<<<dim3(256), dim3(512), 0, stream>>>(h2, wt_fc1, fc1_b, g1);
  // FC2 + residual -> out (fp32), split-K=2: nbx=8, nby=32, grid 512 (kz 0/1)
  gemm_bt<2><<<dim3(512), blk, 0, stream>>>(
      g1, wt_fc2, fc2_b, 4096, 2048, 8, 32,
      out, nullptr, x1, pp, nullptr, nullptr, nullptr);
  // merge split-K partial: out += pp (4M floats = 1M float4)
  add_kernel<<<dim3(2048), blk, 0, stream>>>(out, pp, TROWS * CDIM / 4);
}